// Round 7
// baseline (192.259 us; speedup 1.0000x reference)
//
#include <hip/hip_runtime.h>

// DynamicCache.update concat copy — software-pipelined streaming memcpy, v4.
// past [B,H,S_PAST,D] f32, new [B,H,S_NEW,D] f32.
// d_out = k_out ++ v_out, each [B,H,S_TOT,D] f32.
//
// v4 vs v3: TRIPLE-buffered rolling pipeline (load g+2 / store g) instead of
// double-buffer. Same 96 data VGPRs (3 x GRP=8), but TWO groups of loads
// (256 B/wave) stay in flight continuously vs one (192 B transient) ->
// ~4 KB reads in flight per CU at 16 waves/CU (Little's law: need ~4 KB
// to sustain 3.15 TB/s read stream at ~800 cyc latency).
// ITERS=128 = 16 groups exactly, no remainder. Tails = dedicated front blocks.

typedef float f4 __attribute__((ext_vector_type(4)));

constexpr unsigned B = 4, H = 32, S_PAST = 4096, S_NEW = 16, D = 128;
constexpr unsigned ROW4   = D / 4;              // 32 f4 per row
constexpr unsigned S_TOT  = S_PAST + S_NEW;     // 4112
constexpr unsigned CHUNK4 = S_TOT * ROW4;       // 131584 f4 per (b,h) out-chunk
constexpr unsigned HALF4  = B * H * CHUNK4;     // f4 per out tensor
constexpr unsigned PASTC4 = S_PAST * ROW4;      // 1<<17 f4 per past chunk
constexpr unsigned NEWC4  = S_NEW * ROW4;       // 512 f4 per new chunk
constexpr unsigned PAST_TOTAL4 = 2u * B * H * PASTC4;   // 1<<25
constexpr unsigned MAIN_BLOCKS = 1024;
constexpr unsigned SEG4  = PAST_TOTAL4 / MAIN_BLOCKS;   // 32768 f4 = 512 KB
constexpr unsigned ITERS = SEG4 / 256u;                 // 128 f4 per thread
constexpr unsigned GRP   = 8;
constexpr unsigned NBUF  = 3;
constexpr unsigned NGRP  = ITERS / GRP;                 // 16 groups, exact
constexpr unsigned TAIL_BLOCKS = 2u * B * H;            // 256

__global__ __launch_bounds__(256, 4) void dyncache_copy_kernel(
    const f4* __restrict__ pk, const f4* __restrict__ pv,
    const f4* __restrict__ nk, const f4* __restrict__ nv,
    f4* __restrict__ out)
{
    const unsigned tid = threadIdx.x;

    // ---- new-token tails: dedicated tiny blocks 0..255 (8 KB each) ----
    if (blockIdx.x < TAIL_BLOCKS) {
        const unsigned t  = blockIdx.x >> 7;
        const unsigned bh = blockIdx.x & (B * H - 1);
        const f4* __restrict__ s = (t ? nv : nk) + (size_t)bh * NEWC4;
        f4* __restrict__ d =
            out + (size_t)t * HALF4 + (size_t)bh * CHUNK4 + PASTC4;
        #pragma unroll
        for (unsigned k = 0; k < NEWC4 / 256u; ++k)
            __builtin_nontemporal_store(
                __builtin_nontemporal_load(s + k * 256u + tid), d + k * 256u + tid);
        return;
    }

    // ---- main past copy: one contiguous 512 KB segment per block ----
    const unsigned bid = blockIdx.x - TAIL_BLOCKS;
    const unsigned seg = bid * SEG4;                  // flat past-f4 index
    const unsigned t   = seg >> 24;                   // tensor (k/v)
    const unsigned loc = seg & ((1u << 24) - 1);
    const unsigned bh  = loc >> 17;                   // (b,h) chunk
    const unsigned off = loc & (PASTC4 - 1);          // offset within chunk
    const f4* __restrict__ src =
        (t ? pv : pk) + ((size_t)bh << 17) + off + tid;
    f4* __restrict__ dst =
        out + (size_t)t * HALF4 + (size_t)bh * CHUNK4 + off + tid;

    f4 buf[NBUF][GRP];   // all indices compile-time after full unroll (rule #20)

    // prologue: load groups 0,1
    #pragma unroll
    for (unsigned g = 0; g < 2; ++g)
        #pragma unroll
        for (unsigned j = 0; j < GRP; ++j)
            buf[g][j] = __builtin_nontemporal_load(src + (g * GRP + j) * 256u);

    // steady state: g = 0..13 — load g+2 BEFORE storing g (2 groups of loads
    // always outstanding)
    #pragma unroll
    for (unsigned g = 0; g < NGRP - 2; ++g) {
        #pragma unroll
        for (unsigned j = 0; j < GRP; ++j)
            buf[(g + 2) % NBUF][j] =
                __builtin_nontemporal_load(src + ((g + 2) * GRP + j) * 256u);
        #pragma unroll
        for (unsigned j = 0; j < GRP; ++j)
            __builtin_nontemporal_store(buf[g % NBUF][j],
                                        dst + (g * GRP + j) * 256u);
    }

    // drain: store groups 14,15
    #pragma unroll
    for (unsigned g = NGRP - 2; g < NGRP; ++g)
        #pragma unroll
        for (unsigned j = 0; j < GRP; ++j)
            __builtin_nontemporal_store(buf[g % NBUF][j],
                                        dst + (g * GRP + j) * 256u);
}

extern "C" void kernel_launch(void* const* d_in, const int* in_sizes, int n_in,
                              void* d_out, int out_size, void* d_ws, size_t ws_size,
                              hipStream_t stream) {
    const f4* pk = (const f4*)d_in[0];
    const f4* pv = (const f4*)d_in[1];
    const f4* nk = (const f4*)d_in[2];
    const f4* nv = (const f4*)d_in[3];
    f4* out = (f4*)d_out;

    dyncache_copy_kernel<<<TAIL_BLOCKS + MAIN_BLOCKS, 256, 0, stream>>>(
        pk, pv, nk, nv, out);
}